// Round 9
// baseline (389.351 us; speedup 1.0000x reference)
//
#include <hip/hip_runtime.h>
#include <hip/hip_bf16.h>

typedef __hip_bfloat16 bf16;
typedef __attribute__((ext_vector_type(8))) short short8;   // 8 bf16 = K=32 MFMA A/B frag
typedef __attribute__((ext_vector_type(4))) short short4v;  // 4 bf16 = K=16 MFMA A/B frag
typedef __attribute__((ext_vector_type(4))) float f32x4;    // MFMA C/D frag

#define NB 128   // B*TO
#define CC 64    // channels
#define TT 1024  // time

#if __has_builtin(__builtin_amdgcn_exp2f)
#define EXP2(x) __builtin_amdgcn_exp2f(x)
#else
#define EXP2(x) exp2f(x)
#endif

// ---- cheap bf16 conversion: round-half-up via +0x8000, pack 2 per v_perm ---
__device__ __forceinline__ unsigned rnd_u(float f) {
  return __builtin_bit_cast(unsigned, f) + 0x8000u;
}
__device__ __forceinline__ short f2bfs_fast(float f) {
  return (short)(rnd_u(f) >> 16);
}
// D = [bf16(hi) : bf16(lo)]  (1 v_perm after the two adds)
__device__ __forceinline__ unsigned packbf2(unsigned uhi, unsigned ulo) {
  return __builtin_amdgcn_perm(uhi, ulo, 0x07060302);
}
__device__ __forceinline__ short4v pack4(float a, float b, float c, float d) {
  unsigned pd[2] = { packbf2(rnd_u(b), rnd_u(a)), packbf2(rnd_u(d), rnd_u(c)) };
  return *(const short4v*)pd;
}

__device__ __forceinline__ f32x4 mfma32(short8 a, short8 b, f32x4 c) {
  return __builtin_amdgcn_mfma_f32_16x16x32_bf16(a, b, c, 0, 0, 0);
}
__device__ __forceinline__ f32x4 mfma16(short4v a, short4v b, f32x4 c) {
  return __builtin_amdgcn_mfma_f32_16x16x16bf16_1k(a, b, c, 0, 0, 0);
}

// ---------------------------------------------------------------------------
// Kernel 0: weight convert fp32->bf16 (accurate RNE; one-time). Wq PRE-SCALED
// by scale*log2(e) so scores feed exp2 directly.
// wb: [0:4096) Wq*sl2, [4096:8192) Wk, [8192:12288) Wv, [12288:16384) Wo.
// ---------------------------------------------------------------------------
__global__ __launch_bounds__(256) void wcvt(
    const float* __restrict__ Wq, const float* __restrict__ Wk,
    const float* __restrict__ Wv, const float* __restrict__ Wo,
    const float* __restrict__ scale_p, bf16* __restrict__ wb)
{
  const int i = blockIdx.x * 256 + threadIdx.x;
  float f;
  if      (i <  4096) f = Wq[i] * (*scale_p) * 1.44269504089f;
  else if (i <  8192) f = Wk[i - 4096];
  else if (i < 12288) f = Wv[i - 8192];
  else                f = Wo[i - 12288];
  wb[i] = __float2bfloat16(f);
}

// ---------------------------------------------------------------------------
// Kernel 1: MFMA q/k/v projections. All fp32->bf16 conversions use the cheap
// +0x8000 round (r8 post-mortem: library RNE ~5 VALU inst each, 64/thread).
// qt/kt in [n][t][c], v in [n][c][t].
// ---------------------------------------------------------------------------
__global__ __launch_bounds__(256) void qkv_mfma(
    const float* __restrict__ x, const bf16* __restrict__ wb,
    bf16* __restrict__ qt, bf16* __restrict__ kt, bf16* __restrict__ v)
{
  __shared__ short xs[64 * 72];   // x^T tile [t][c]
  __shared__ short ys[64 * 72];   // output assembly buffer

  const int n  = blockIdx.y;
  const int t0 = blockIdx.x * 64;
  const int tid = threadIdx.x;
  const int w  = tid >> 6, il = tid & 15, q4 = (tid & 63) >> 4;
  const size_t nbase = (size_t)n * (CC * TT);

  {
    const int tc = tid & 15;
    const int c0 = (tid >> 4) * 4;
    float fe[4][4];
    #pragma unroll
    for (int j = 0; j < 4; j++) {
      float4 fj = *(const float4*)&x[nbase + (size_t)(c0 + j) * TT + t0 + tc * 4];
      fe[j][0] = fj.x; fe[j][1] = fj.y; fe[j][2] = fj.z; fe[j][3] = fj.w;
    }
    #pragma unroll
    for (int e = 0; e < 4; e++)
      *(short4v*)&xs[(tc * 4 + e) * 72 + c0] = pack4(fe[0][e], fe[1][e], fe[2][e], fe[3][e]);
  }
  __syncthreads();

  short8 xa[2];
  #pragma unroll
  for (int kk = 0; kk < 2; kk++)
    xa[kk] = *(const short8*)&xs[(w * 16 + il) * 72 + kk * 32 + q4 * 8];

  const bf16* wq = wb;
  const bf16* wk = wb + 4096;
  const bf16* wv = wb + 8192;

  f32x4 aq[4], ak[4], av[4];
  #pragma unroll
  for (int i = 0; i < 4; i++) {
    aq[i] = (f32x4){0.f,0.f,0.f,0.f};
    ak[i] = (f32x4){0.f,0.f,0.f,0.f};
    av[i] = (f32x4){0.f,0.f,0.f,0.f};
  }

  #pragma unroll
  for (int kk = 0; kk < 2; kk++) {
    #pragma unroll
    for (int ot = 0; ot < 4; ot++) {
      const int ridx = (ot * 16 + il) * 64 + kk * 32 + q4 * 8;
      short8 bq = *(const short8*)&wq[ridx];
      short8 bk = *(const short8*)&wk[ridx];
      short8 bv = *(const short8*)&wv[ridx];
      aq[ot] = mfma32(xa[kk], bq, aq[ot]);   // D[t][o]
      ak[ot] = mfma32(xa[kk], bk, ak[ot]);   // D[t][o]
      av[ot] = mfma32(bv, xa[kk], av[ot]);   // D[o][t]
    }
  }

  const int rr = tid >> 2;
  const int sg = (tid & 3) * 8;

  __syncthreads();
  #pragma unroll
  for (int ot = 0; ot < 4; ot++)
    #pragma unroll
    for (int r = 0; r < 4; r++)
      ys[(w * 16 + q4 * 4 + r) * 72 + ot * 16 + il] = f2bfs_fast(aq[ot][r]);
  __syncthreads();
  *(short8*)&qt[nbase + (size_t)(t0 + rr) * 64 + sg]      = *(const short8*)&ys[rr * 72 + sg];
  *(short8*)&qt[nbase + (size_t)(t0 + rr) * 64 + sg + 32] = *(const short8*)&ys[rr * 72 + sg + 32];

  __syncthreads();
  #pragma unroll
  for (int ot = 0; ot < 4; ot++)
    #pragma unroll
    for (int r = 0; r < 4; r++)
      ys[(w * 16 + q4 * 4 + r) * 72 + ot * 16 + il] = f2bfs_fast(ak[ot][r]);
  __syncthreads();
  *(short8*)&kt[nbase + (size_t)(t0 + rr) * 64 + sg]      = *(const short8*)&ys[rr * 72 + sg];
  *(short8*)&kt[nbase + (size_t)(t0 + rr) * 64 + sg + 32] = *(const short8*)&ys[rr * 72 + sg + 32];

  __syncthreads();
  #pragma unroll
  for (int ot = 0; ot < 4; ot++)
    #pragma unroll
    for (int r = 0; r < 4; r++)
      ys[(ot * 16 + q4 * 4 + r) * 72 + w * 16 + il] = f2bfs_fast(av[ot][r]);
  __syncthreads();
  *(short8*)&v[nbase + (size_t)rr * TT + t0 + sg]      = *(const short8*)&ys[rr * 72 + sg];
  *(short8*)&v[nbase + (size_t)rr * TT + t0 + sg + 32] = *(const short8*)&ys[rr * 72 + sg + 32];
}

// ---------------------------------------------------------------------------
// Kernel 2: flash attention + Wo + residual; transposed-S; register-pipelined
// staging; 64-QUERY blocks (grid 2048 -> 8 blocks/CU; r8 was grid-capped at
// 4 blocks/CU = 50% occupancy). Wave owns 16 q (1 m-tile, t = MFMA n-dim).
// No online max (scores bounded; softmax shift-invariant; validated r6-r8).
// S^T = K(A) x Q(B) pre-scaled (Wq fold); P packs via +0x8000/v_perm and
// feeds PV's K=16 MFMA straight from registers (C/D == K=16 B-frag layout).
// Layouts (m89/m120-verified): A[m=lane&15][k=quad*8+j];
// B[k=quad*8+j][n=lane&15]; C/D row=quad*4+reg, col=lane&15; K=16: k=quad*4+j.
// ---------------------------------------------------------------------------
__global__ __launch_bounds__(256, 8) void attn_flash(
    const bf16* __restrict__ qt, const bf16* __restrict__ kt,
    const bf16* __restrict__ v,  const bf16* __restrict__ wob,
    const float* __restrict__ x, float* __restrict__ out)
{
  __shared__ short ks[64 * 72];     // K tile [s][c]
  __shared__ short vs[64 * 72];     // V tile [c][s]

  const int bid = blockIdx.x;
  const int n   = bid & 127;        // bid%8 == n%8 -> same-n blocks share an XCD
  const int qt0 = (bid >> 7) * 64;
  const int tid = threadIdx.x;
  const int w   = tid >> 6;
  const int il  = tid & 15;
  const int q4  = (tid & 63) >> 4;
  const size_t nbase = (size_t)n * (CC * TT);

  // staging coords: 2 chunks of 16B each for K and V
  const int srow0 = tid >> 3, scol = (tid & 7) * 8;
  const int srow1 = srow0 + 32;

  // persistent Q B-frags (pre-scaled): B[k=c][n=t], wave's 16 queries
  short8 qb[2];
  #pragma unroll
  for (int kk = 0; kk < 2; kk++)
    qb[kk] = *(const short8*)&qt[nbase +
        (size_t)(qt0 + w * 16 + il) * 64 + kk * 32 + q4 * 8];

  f32x4 oaccT[4];                   // [ct]: O^T[c][t], c=ct*16+q4*4+r, t=il
  float lst = 0.f;
  #pragma unroll
  for (int ct = 0; ct < 4; ct++) oaccT[ct] = (f32x4){0.f, 0.f, 0.f, 0.f};

  // prefetch tile 0 into registers
  short8 kreg0 = *(const short8*)&kt[nbase + (size_t)srow0 * 64 + scol];
  short8 kreg1 = *(const short8*)&kt[nbase + (size_t)srow1 * 64 + scol];
  short8 vreg0 = *(const short8*)&v[nbase + (size_t)srow0 * TT + scol];
  short8 vreg1 = *(const short8*)&v[nbase + (size_t)srow1 * TT + scol];

  #pragma unroll 1
  for (int st = 0; st < 16; st++) {
    __syncthreads();                     // prev-iter compute reads of ks/vs done
    *(short8*)&ks[srow0 * 72 + scol] = kreg0;
    *(short8*)&ks[srow1 * 72 + scol] = kreg1;
    *(short8*)&vs[srow0 * 72 + scol] = vreg0;
    *(short8*)&vs[srow1 * 72 + scol] = vreg1;
    if (st < 15) {                       // prefetch st+1: in flight across barrier
      const int s1 = (st + 1) * 64;
      kreg0 = *(const short8*)&kt[nbase + (size_t)(s1 + srow0) * 64 + scol];
      kreg1 = *(const short8*)&kt[nbase + (size_t)(s1 + srow1) * 64 + scol];
      vreg0 = *(const short8*)&v[nbase + (size_t)srow0 * TT + s1 + scol];
      vreg1 = *(const short8*)&v[nbase + (size_t)srow1 * TT + s1 + scol];
    }
    __syncthreads();                     // ks/vs visible

    #pragma unroll
    for (int st2 = 0; st2 < 4; st2++) {
      short8 ka0 = *(const short8*)&ks[(st2 * 16 + il) * 72 + q4 * 8];
      short8 ka1 = *(const short8*)&ks[(st2 * 16 + il) * 72 + 32 + q4 * 8];

      f32x4 sT = (f32x4){0.f, 0.f, 0.f, 0.f};
      sT = mfma32(ka0, qb[0], sT);
      sT = mfma32(ka1, qb[1], sT);

      // exp (shift-free, pre-scaled) + cheap bf16 pack (3 VALU / 2 vals)
      float p0 = EXP2(sT[0]), p1 = EXP2(sT[1]), p2 = EXP2(sT[2]), p3 = EXP2(sT[3]);
      lst += (p0 + p1) + (p2 + p3);
      unsigned pd[2] = { packbf2(rnd_u(p1), rnd_u(p0)),
                         packbf2(rnd_u(p3), rnd_u(p2)) };
      short4v pf = *(const short4v*)pd;

      #pragma unroll
      for (int ct = 0; ct < 4; ct++) {
        short4v va = *(const short4v*)&vs[(ct * 16 + il) * 72 + st2 * 16 + q4 * 4];
        oaccT[ct] = mfma16(va, pf, oaccT[ct]);
      }
    }
  }

  // ================= epilogue ==============================================
  float l = lst;
  l += __shfl_xor(l, 16, 64);
  l += __shfl_xor(l, 32, 64);
  const float linv = 1.f / l;

  // O^T regs -> bf16 B-frags (k=c=q4*4+j == K=16 B layout)
  short4v ob[4];
  #pragma unroll
  for (int ct = 0; ct < 4; ct++)
    ob[ct] = pack4(oaccT[ct][0] * linv, oaccT[ct][1] * linv,
                   oaccT[ct][2] * linv, oaccT[ct][3] * linv);

  // res[o][t] = Wo(A) x O(B), K=16 over 4 ct chunks; direct store + residual
  #pragma unroll
  for (int ot = 0; ot < 4; ot++) {
    short4v wa[4];
    #pragma unroll
    for (int ct = 0; ct < 4; ct++)
      wa[ct] = *(const short4v*)&wob[(ot * 16 + il) * 64 + ct * 16 + q4 * 4];
    f32x4 res = (f32x4){0.f, 0.f, 0.f, 0.f};
    #pragma unroll
    for (int ct = 0; ct < 4; ct++)
      res = mfma16(wa[ct], ob[ct], res);
    const int tg = qt0 + w * 16 + il;
    #pragma unroll
    for (int r = 0; r < 4; r++) {
      const size_t idx = nbase + (size_t)(ot * 16 + q4 * 4 + r) * TT + tg;
      out[idx] = res[r] + x[idx];
    }
  }
}

// ---------------------------------------------------------------------------
extern "C" void kernel_launch(void* const* d_in, const int* in_sizes, int n_in,
                              void* d_out, int out_size, void* d_ws, size_t ws_size,
                              hipStream_t stream) {
  const float* x     = (const float*)d_in[0];
  const float* Wq    = (const float*)d_in[1];
  const float* Wk    = (const float*)d_in[2];
  const float* Wv    = (const float*)d_in[3];
  const float* Wo    = (const float*)d_in[4];
  const float* scale = (const float*)d_in[5];
  float* out = (float*)d_out;

  const size_t elems = (size_t)NB * CC * TT;
  bf16* wb  = (bf16*)d_ws;          // 16384 bf16 weights
  bf16* qtb = wb + 16384;
  bf16* ktb = qtb + elems;
  bf16* vv  = ktb + elems;

  wcvt<<<64, 256, 0, stream>>>(Wq, Wk, Wv, Wo, scale, wb);
  qkv_mfma<<<dim3(TT / 64, NB), 256, 0, stream>>>(x, wb, qtb, ktb, vv);
  attn_flash<<<dim3(NB * (TT / 64)), 256, 0, stream>>>(qtb, ktb, vv, wb + 12288, x, out);
}

// Round 11
// 187.987 us; speedup vs baseline: 2.0712x; 2.0712x over previous
//
#include <hip/hip_runtime.h>
#include <hip/hip_bf16.h>

typedef __hip_bfloat16 bf16;
typedef __attribute__((ext_vector_type(8))) short short8;   // 8 bf16 = K=32 MFMA A/B frag
typedef __attribute__((ext_vector_type(4))) short short4v;  // 4 bf16 = K=16 MFMA A/B frag
typedef __attribute__((ext_vector_type(4))) float f32x4;    // MFMA C/D frag

#define NB 128   // B*TO
#define CC 64    // channels
#define TT 1024  // time

#if __has_builtin(__builtin_amdgcn_exp2f)
#define EXP2(x) __builtin_amdgcn_exp2f(x)
#else
#define EXP2(x) exp2f(x)
#endif

// ---- cheap bf16 conversion: round-half-up via +0x8000, pack 2 per v_perm ---
__device__ __forceinline__ unsigned rnd_u(float f) {
  return __builtin_bit_cast(unsigned, f) + 0x8000u;
}
__device__ __forceinline__ short f2bfs_fast(float f) {
  return (short)(rnd_u(f) >> 16);
}
__device__ __forceinline__ unsigned packbf2(unsigned uhi, unsigned ulo) {
  return __builtin_amdgcn_perm(uhi, ulo, 0x07060302);
}
__device__ __forceinline__ short4v pack4(float a, float b, float c, float d) {
  unsigned pd[2] = { packbf2(rnd_u(b), rnd_u(a)), packbf2(rnd_u(d), rnd_u(c)) };
  return *(const short4v*)pd;
}

__device__ __forceinline__ f32x4 mfma32(short8 a, short8 b, f32x4 c) {
  return __builtin_amdgcn_mfma_f32_16x16x32_bf16(a, b, c, 0, 0, 0);
}
__device__ __forceinline__ f32x4 mfma16(short4v a, short4v b, f32x4 c) {
  return __builtin_amdgcn_mfma_f32_16x16x16bf16_1k(a, b, c, 0, 0, 0);
}

// ---------------------------------------------------------------------------
// Kernel 0: weight convert fp32->bf16 (one-time). Wq PRE-SCALED by
// scale*log2(e) so scores feed exp2 directly.
// wb: [0:4096) Wq*sl2, [4096:8192) Wk, [8192:12288) Wv, [12288:16384) Wo.
// ---------------------------------------------------------------------------
__global__ __launch_bounds__(256) void wcvt(
    const float* __restrict__ Wq, const float* __restrict__ Wk,
    const float* __restrict__ Wv, const float* __restrict__ Wo,
    const float* __restrict__ scale_p, bf16* __restrict__ wb)
{
  const int i = blockIdx.x * 256 + threadIdx.x;
  float f;
  if      (i <  4096) f = Wq[i] * (*scale_p) * 1.44269504089f;
  else if (i <  8192) f = Wk[i - 4096];
  else if (i < 12288) f = Wv[i - 8192];
  else                f = Wo[i - 12288];
  wb[i] = __float2bfloat16(f);
}

// ---------------------------------------------------------------------------
// Kernel 1: MFMA q/k/v projections; cheap +0x8000 bf16 rounding (r9-validated).
// qt/kt in [n][t][c], v in [n][c][t].
// ---------------------------------------------------------------------------
__global__ __launch_bounds__(256) void qkv_mfma(
    const float* __restrict__ x, const bf16* __restrict__ wb,
    bf16* __restrict__ qt, bf16* __restrict__ kt, bf16* __restrict__ v)
{
  __shared__ short xs[64 * 72];   // x^T tile [t][c]
  __shared__ short ys[64 * 72];   // output assembly buffer

  const int n  = blockIdx.y;
  const int t0 = blockIdx.x * 64;
  const int tid = threadIdx.x;
  const int w  = tid >> 6, il = tid & 15, q4 = (tid & 63) >> 4;
  const size_t nbase = (size_t)n * (CC * TT);

  {
    const int tc = tid & 15;
    const int c0 = (tid >> 4) * 4;
    float fe[4][4];
    #pragma unroll
    for (int j = 0; j < 4; j++) {
      float4 fj = *(const float4*)&x[nbase + (size_t)(c0 + j) * TT + t0 + tc * 4];
      fe[j][0] = fj.x; fe[j][1] = fj.y; fe[j][2] = fj.z; fe[j][3] = fj.w;
    }
    #pragma unroll
    for (int e = 0; e < 4; e++)
      *(short4v*)&xs[(tc * 4 + e) * 72 + c0] = pack4(fe[0][e], fe[1][e], fe[2][e], fe[3][e]);
  }
  __syncthreads();

  short8 xa[2];
  #pragma unroll
  for (int kk = 0; kk < 2; kk++)
    xa[kk] = *(const short8*)&xs[(w * 16 + il) * 72 + kk * 32 + q4 * 8];

  const bf16* wq = wb;
  const bf16* wk = wb + 4096;
  const bf16* wv = wb + 8192;

  f32x4 aq[4], ak[4], av[4];
  #pragma unroll
  for (int i = 0; i < 4; i++) {
    aq[i] = (f32x4){0.f,0.f,0.f,0.f};
    ak[i] = (f32x4){0.f,0.f,0.f,0.f};
    av[i] = (f32x4){0.f,0.f,0.f,0.f};
  }

  #pragma unroll
  for (int kk = 0; kk < 2; kk++) {
    #pragma unroll
    for (int ot = 0; ot < 4; ot++) {
      const int ridx = (ot * 16 + il) * 64 + kk * 32 + q4 * 8;
      short8 bq = *(const short8*)&wq[ridx];
      short8 bk = *(const short8*)&wk[ridx];
      short8 bv = *(const short8*)&wv[ridx];
      aq[ot] = mfma32(xa[kk], bq, aq[ot]);   // D[t][o]
      ak[ot] = mfma32(xa[kk], bk, ak[ot]);   // D[t][o]
      av[ot] = mfma32(bv, xa[kk], av[ot]);   // D[o][t]
    }
  }

  const int rr = tid >> 2;
  const int sg = (tid & 3) * 8;

  __syncthreads();
  #pragma unroll
  for (int ot = 0; ot < 4; ot++)
    #pragma unroll
    for (int r = 0; r < 4; r++)
      ys[(w * 16 + q4 * 4 + r) * 72 + ot * 16 + il] = f2bfs_fast(aq[ot][r]);
  __syncthreads();
  *(short8*)&qt[nbase + (size_t)(t0 + rr) * 64 + sg]      = *(const short8*)&ys[rr * 72 + sg];
  *(short8*)&qt[nbase + (size_t)(t0 + rr) * 64 + sg + 32] = *(const short8*)&ys[rr * 72 + sg + 32];

  __syncthreads();
  #pragma unroll
  for (int ot = 0; ot < 4; ot++)
    #pragma unroll
    for (int r = 0; r < 4; r++)
      ys[(w * 16 + q4 * 4 + r) * 72 + ot * 16 + il] = f2bfs_fast(ak[ot][r]);
  __syncthreads();
  *(short8*)&kt[nbase + (size_t)(t0 + rr) * 64 + sg]      = *(const short8*)&ys[rr * 72 + sg];
  *(short8*)&kt[nbase + (size_t)(t0 + rr) * 64 + sg + 32] = *(const short8*)&ys[rr * 72 + sg + 32];

  __syncthreads();
  #pragma unroll
  for (int ot = 0; ot < 4; ot++)
    #pragma unroll
    for (int r = 0; r < 4; r++)
      ys[(ot * 16 + q4 * 4 + r) * 72 + w * 16 + il] = f2bfs_fast(av[ot][r]);
  __syncthreads();
  *(short8*)&v[nbase + (size_t)rr * TT + t0 + sg]      = *(const short8*)&ys[rr * 72 + sg];
  *(short8*)&v[nbase + (size_t)rr * TT + t0 + sg + 32] = *(const short8*)&ys[rr * 72 + sg + 32];
}

// ---------------------------------------------------------------------------
// Kernel 2: flash attention + Wo + residual — EXACT r8 structure (the proven-
// stable config: 128-q blocks, (256,4), grid 1024, VGPR 64, 50+ clean graph
// replays) with r9's correctness-validated micro-opts folded in (raw v_exp_f32
// + cheap +0x8000/v_perm bf16 pack). r9's 64q/(256,8) spilled (652 MB scratch)
// and r10's (256,6) failed the post-timing determinism tripwire — occupancy
// >4 blocks/CU is closed as an avenue on this structure.
// Transposed-S: S^T = K(A) x Q(B), pre-scaled via Wq fold; no online max
// (scores bounded, shift-invariant; validated r6-r9); P feeds PV's K=16 MFMA
// straight from registers (C/D layout == K=16 B-frag layout).
// Layouts (m89/m120-verified): A[m=lane&15][k=quad*8+j];
// B[k=quad*8+j][n=lane&15]; C/D row=quad*4+reg, col=lane&15; K=16: k=quad*4+j.
// ---------------------------------------------------------------------------
__global__ __launch_bounds__(256, 4) void attn_flash(
    const bf16* __restrict__ qt, const bf16* __restrict__ kt,
    const bf16* __restrict__ v,  const bf16* __restrict__ wob,
    const float* __restrict__ x, float* __restrict__ out)
{
  __shared__ short ks[64 * 72];     // K tile [s][c]
  __shared__ short vs[64 * 72];     // V tile [c][s]

  const int bid = blockIdx.x;
  const int n   = bid & 127;        // bid%8 == n%8 -> same-n blocks share an XCD
  const int qt0 = (bid >> 7) * 128;
  const int tid = threadIdx.x;
  const int w   = tid >> 6;
  const int il  = tid & 15;
  const int q4  = (tid & 63) >> 4;
  const size_t nbase = (size_t)n * (CC * TT);

  // staging coords: 2 chunks of 16B each for K and V
  const int srow0 = tid >> 3, scol = (tid & 7) * 8;
  const int srow1 = srow0 + 32;

  // persistent Q B-frags (pre-scaled): B[k=c][n=t], wave's 32 queries
  short8 qb[2][2];
  #pragma unroll
  for (int mt = 0; mt < 2; mt++)
    #pragma unroll
    for (int kk = 0; kk < 2; kk++)
      qb[mt][kk] = *(const short8*)&qt[nbase +
          (size_t)(qt0 + w * 32 + mt * 16 + il) * 64 + kk * 32 + q4 * 8];

  f32x4 oaccT[2][4];                // [mt][ct]: O^T[c][t], c=ct*16+q4*4+r, t=mt*16+il
  float lst[2] = {0.f, 0.f};
  #pragma unroll
  for (int mt = 0; mt < 2; mt++)
    #pragma unroll
    for (int ct = 0; ct < 4; ct++) oaccT[mt][ct] = (f32x4){0.f, 0.f, 0.f, 0.f};

  // prefetch tile 0 into registers
  short8 kreg0 = *(const short8*)&kt[nbase + (size_t)srow0 * 64 + scol];
  short8 kreg1 = *(const short8*)&kt[nbase + (size_t)srow1 * 64 + scol];
  short8 vreg0 = *(const short8*)&v[nbase + (size_t)srow0 * TT + scol];
  short8 vreg1 = *(const short8*)&v[nbase + (size_t)srow1 * TT + scol];

  #pragma unroll 1
  for (int st = 0; st < 16; st++) {
    __syncthreads();                     // prev-iter compute reads of ks/vs done
    *(short8*)&ks[srow0 * 72 + scol] = kreg0;
    *(short8*)&ks[srow1 * 72 + scol] = kreg1;
    *(short8*)&vs[srow0 * 72 + scol] = vreg0;
    *(short8*)&vs[srow1 * 72 + scol] = vreg1;
    if (st < 15) {                       // prefetch st+1: in flight across barrier
      const int s1 = (st + 1) * 64;
      kreg0 = *(const short8*)&kt[nbase + (size_t)(s1 + srow0) * 64 + scol];
      kreg1 = *(const short8*)&kt[nbase + (size_t)(s1 + srow1) * 64 + scol];
      vreg0 = *(const short8*)&v[nbase + (size_t)srow0 * TT + s1 + scol];
      vreg1 = *(const short8*)&v[nbase + (size_t)srow1 * TT + s1 + scol];
    }
    __syncthreads();                     // ks/vs visible

    #pragma unroll
    for (int st2 = 0; st2 < 4; st2++) {
      short8 ka0 = *(const short8*)&ks[(st2 * 16 + il) * 72 + q4 * 8];
      short8 ka1 = *(const short8*)&ks[(st2 * 16 + il) * 72 + 32 + q4 * 8];
      short4v va[4];
      #pragma unroll
      for (int ct = 0; ct < 4; ct++)
        va[ct] = *(const short4v*)&vs[(ct * 16 + il) * 72 + st2 * 16 + q4 * 4];

      #pragma unroll
      for (int mt = 0; mt < 2; mt++) {
        f32x4 sT = (f32x4){0.f, 0.f, 0.f, 0.f};
        sT = mfma32(ka0, qb[mt][0], sT);
        sT = mfma32(ka1, qb[mt][1], sT);

        // exp (shift-free, pre-scaled) + cheap bf16 pack (3 VALU / 2 vals)
        float p0 = EXP2(sT[0]), p1 = EXP2(sT[1]), p2 = EXP2(sT[2]), p3 = EXP2(sT[3]);
        lst[mt] += (p0 + p1) + (p2 + p3);
        unsigned pd[2] = { packbf2(rnd_u(p1), rnd_u(p0)),
                           packbf2(rnd_u(p3), rnd_u(p2)) };
        short4v pf = *(const short4v*)pd;

        #pragma unroll
        for (int ct = 0; ct < 4; ct++)
          oaccT[mt][ct] = mfma16(va[ct], pf, oaccT[mt][ct]);
      }
    }
  }

  // ================= epilogue ==============================================
  float linv[2];
  #pragma unroll
  for (int mt = 0; mt < 2; mt++) {
    float l = lst[mt];
    l += __shfl_xor(l, 16, 64);
    l += __shfl_xor(l, 32, 64);
    linv[mt] = 1.f / l;
  }

  // O^T regs -> bf16 B-frags (k=c=q4*4+j == K=16 B layout)
  short4v ob[2][4];
  #pragma unroll
  for (int mt = 0; mt < 2; mt++)
    #pragma unroll
    for (int ct = 0; ct < 4; ct++)
      ob[mt][ct] = pack4(oaccT[mt][ct][0] * linv[mt], oaccT[mt][ct][1] * linv[mt],
                         oaccT[mt][ct][2] * linv[mt], oaccT[mt][ct][3] * linv[mt]);

  // res[o][t] = Wo(A) x O(B), K=16 over 4 ct chunks; direct store + residual
  #pragma unroll
  for (int ot = 0; ot < 4; ot++) {
    short4v wa[4];
    #pragma unroll
    for (int ct = 0; ct < 4; ct++)
      wa[ct] = *(const short4v*)&wob[(ot * 16 + il) * 64 + ct * 16 + q4 * 4];
    #pragma unroll
    for (int mt = 0; mt < 2; mt++) {
      f32x4 res = (f32x4){0.f, 0.f, 0.f, 0.f};
      #pragma unroll
      for (int ct = 0; ct < 4; ct++)
        res = mfma16(wa[ct], ob[mt][ct], res);
      const int tg = qt0 + w * 32 + mt * 16 + il;
      #pragma unroll
      for (int r = 0; r < 4; r++) {
        const size_t idx = nbase + (size_t)(ot * 16 + q4 * 4 + r) * TT + tg;
        out[idx] = res[r] + x[idx];
      }
    }
  }
}

// ---------------------------------------------------------------------------
extern "C" void kernel_launch(void* const* d_in, const int* in_sizes, int n_in,
                              void* d_out, int out_size, void* d_ws, size_t ws_size,
                              hipStream_t stream) {
  const float* x     = (const float*)d_in[0];
  const float* Wq    = (const float*)d_in[1];
  const float* Wk    = (const float*)d_in[2];
  const float* Wv    = (const float*)d_in[3];
  const float* Wo    = (const float*)d_in[4];
  const float* scale = (const float*)d_in[5];
  float* out = (float*)d_out;

  const size_t elems = (size_t)NB * CC * TT;
  bf16* wb  = (bf16*)d_ws;          // 16384 bf16 weights
  bf16* qtb = wb + 16384;
  bf16* ktb = qtb + elems;
  bf16* vv  = ktb + elems;

  wcvt<<<64, 256, 0, stream>>>(Wq, Wk, Wv, Wo, scale, wb);
  qkv_mfma<<<dim3(TT / 64, NB), 256, 0, stream>>>(x, wb, qtb, ktb, vv);
  attn_flash<<<dim3(NB * (TT / 128)), 256, 0, stream>>>(qtb, ktb, vv, wb + 12288, x, out);
}

// Round 12
// 163.277 us; speedup vs baseline: 2.3846x; 1.1513x over previous
//
#include <hip/hip_runtime.h>
#include <hip/hip_bf16.h>

typedef __hip_bfloat16 bf16;
typedef __attribute__((ext_vector_type(8))) short short8;   // 8 bf16 = K=32 MFMA A/B frag
typedef __attribute__((ext_vector_type(4))) short short4v;  // 4 bf16 = K=16 MFMA A/B frag
typedef __attribute__((ext_vector_type(4))) float f32x4;    // MFMA C/D frag

#define NB 128   // B*TO
#define CC 64    // channels
#define TT 1024  // time

#if __has_builtin(__builtin_amdgcn_exp2f)
#define EXP2(x) __builtin_amdgcn_exp2f(x)
#else
#define EXP2(x) exp2f(x)
#endif

// ---- cheap bf16 conversion: round-half-up via +0x8000, pack 2 per v_perm ---
__device__ __forceinline__ unsigned rnd_u(float f) {
  return __builtin_bit_cast(unsigned, f) + 0x8000u;
}
__device__ __forceinline__ short f2bfs_fast(float f) {
  return (short)(rnd_u(f) >> 16);
}
__device__ __forceinline__ unsigned packbf2(unsigned uhi, unsigned ulo) {
  return __builtin_amdgcn_perm(uhi, ulo, 0x07060302);
}
__device__ __forceinline__ short4v pack4(float a, float b, float c, float d) {
  unsigned pd[2] = { packbf2(rnd_u(b), rnd_u(a)), packbf2(rnd_u(d), rnd_u(c)) };
  return *(const short4v*)pd;
}

__device__ __forceinline__ f32x4 mfma32(short8 a, short8 b, f32x4 c) {
  return __builtin_amdgcn_mfma_f32_16x16x32_bf16(a, b, c, 0, 0, 0);
}
__device__ __forceinline__ f32x4 mfma16(short4v a, short4v b, f32x4 c) {
  return __builtin_amdgcn_mfma_f32_16x16x16bf16_1k(a, b, c, 0, 0, 0);
}

// ---------------------------------------------------------------------------
// Kernel 0: weight convert fp32->bf16 (one-time). Wq PRE-SCALED by
// scale*log2(e) so scores feed exp2 directly.
// ---------------------------------------------------------------------------
__global__ __launch_bounds__(256) void wcvt(
    const float* __restrict__ Wq, const float* __restrict__ Wk,
    const float* __restrict__ Wv, const float* __restrict__ Wo,
    const float* __restrict__ scale_p, bf16* __restrict__ wb)
{
  const int i = blockIdx.x * 256 + threadIdx.x;
  float f;
  if      (i <  4096) f = Wq[i] * (*scale_p) * 1.44269504089f;
  else if (i <  8192) f = Wk[i - 4096];
  else if (i < 12288) f = Wv[i - 8192];
  else                f = Wo[i - 12288];
  wb[i] = __float2bfloat16(f);
}

// ---------------------------------------------------------------------------
// Kernel 1: MFMA q/k/v projections. qt/kt in [n][t][c].
// V is written in a PERMUTED [n][c][s'] layout: within each 64-s block,
// s = a*16+b*4+j is stored at s' = b*16+a*4+j. This lets attn read one b128
// from LDS and get PV A-frags for all four 16-s strips (r12 change).
// ---------------------------------------------------------------------------
__global__ __launch_bounds__(256) void qkv_mfma(
    const float* __restrict__ x, const bf16* __restrict__ wb,
    bf16* __restrict__ qt, bf16* __restrict__ kt, bf16* __restrict__ v)
{
  __shared__ short xs[64 * 72];   // x^T tile [t][c]
  __shared__ short ys[64 * 72];   // output assembly buffer

  const int n  = blockIdx.y;
  const int t0 = blockIdx.x * 64;
  const int tid = threadIdx.x;
  const int w  = tid >> 6, il = tid & 15, q4 = (tid & 63) >> 4;
  const size_t nbase = (size_t)n * (CC * TT);

  {
    const int tc = tid & 15;
    const int c0 = (tid >> 4) * 4;
    float fe[4][4];
    #pragma unroll
    for (int j = 0; j < 4; j++) {
      float4 fj = *(const float4*)&x[nbase + (size_t)(c0 + j) * TT + t0 + tc * 4];
      fe[j][0] = fj.x; fe[j][1] = fj.y; fe[j][2] = fj.z; fe[j][3] = fj.w;
    }
    #pragma unroll
    for (int e = 0; e < 4; e++)
      *(short4v*)&xs[(tc * 4 + e) * 72 + c0] = pack4(fe[0][e], fe[1][e], fe[2][e], fe[3][e]);
  }
  __syncthreads();

  short8 xa[2];
  #pragma unroll
  for (int kk = 0; kk < 2; kk++)
    xa[kk] = *(const short8*)&xs[(w * 16 + il) * 72 + kk * 32 + q4 * 8];

  const bf16* wq = wb;
  const bf16* wk = wb + 4096;
  const bf16* wv = wb + 8192;

  f32x4 aq[4], ak[4], av[4];
  #pragma unroll
  for (int i = 0; i < 4; i++) {
    aq[i] = (f32x4){0.f,0.f,0.f,0.f};
    ak[i] = (f32x4){0.f,0.f,0.f,0.f};
    av[i] = (f32x4){0.f,0.f,0.f,0.f};
  }

  #pragma unroll
  for (int kk = 0; kk < 2; kk++) {
    #pragma unroll
    for (int ot = 0; ot < 4; ot++) {
      const int ridx = (ot * 16 + il) * 64 + kk * 32 + q4 * 8;
      short8 bq = *(const short8*)&wq[ridx];
      short8 bk = *(const short8*)&wk[ridx];
      short8 bv = *(const short8*)&wv[ridx];
      aq[ot] = mfma32(xa[kk], bq, aq[ot]);   // D[t][o]
      ak[ot] = mfma32(xa[kk], bk, ak[ot]);   // D[t][o]
      av[ot] = mfma32(bv, xa[kk], av[ot]);   // D[o][t]
    }
  }

  const int rr = tid >> 2;
  const int sg = (tid & 3) * 8;

  __syncthreads();
  #pragma unroll
  for (int ot = 0; ot < 4; ot++)
    #pragma unroll
    for (int r = 0; r < 4; r++)
      ys[(w * 16 + q4 * 4 + r) * 72 + ot * 16 + il] = f2bfs_fast(aq[ot][r]);
  __syncthreads();
  *(short8*)&qt[nbase + (size_t)(t0 + rr) * 64 + sg]      = *(const short8*)&ys[rr * 72 + sg];
  *(short8*)&qt[nbase + (size_t)(t0 + rr) * 64 + sg + 32] = *(const short8*)&ys[rr * 72 + sg + 32];

  __syncthreads();
  #pragma unroll
  for (int ot = 0; ot < 4; ot++)
    #pragma unroll
    for (int r = 0; r < 4; r++)
      ys[(w * 16 + q4 * 4 + r) * 72 + ot * 16 + il] = f2bfs_fast(ak[ot][r]);
  __syncthreads();
  *(short8*)&kt[nbase + (size_t)(t0 + rr) * 64 + sg]      = *(const short8*)&ys[rr * 72 + sg];
  *(short8*)&kt[nbase + (size_t)(t0 + rr) * 64 + sg + 32] = *(const short8*)&ys[rr * 72 + sg + 32];

  __syncthreads();
  // V with permuted s-column: t_local = w*16+il -> col (il>>2)*16 + w*4 + (il&3)
  #pragma unroll
  for (int ot = 0; ot < 4; ot++)
    #pragma unroll
    for (int r = 0; r < 4; r++)
      ys[(ot * 16 + q4 * 4 + r) * 72 + (il >> 2) * 16 + w * 4 + (il & 3)] =
          f2bfs_fast(av[ot][r]);
  __syncthreads();
  *(short8*)&v[nbase + (size_t)rr * TT + t0 + sg]      = *(const short8*)&ys[rr * 72 + sg];
  *(short8*)&v[nbase + (size_t)rr * TT + t0 + sg + 32] = *(const short8*)&ys[rr * 72 + sg + 32];
}

// ---------------------------------------------------------------------------
// Kernel 2: flash attention + Wo + residual. r11 structure (proven-stable
// (256,4), 128-q blocks, grid 1024) + three r12 changes:
//  (1) coalesced fp32 epilogue through obuf (r11 WRITE_SIZE was 93.8 MB for a
//      33.5 MB output: partial-line scattered stores; now full 128B lines),
//  (2) permuted-V LDS layout: one b128 read = PV A-frags for all 4 strips
//      (va reads 16xb64 -> 8xb128/wave-iter); P frags for all strips in regs,
//  (3) softmax denominator via ones-MFMA (lacc) instead of 32 VALU adds/iter.
// No online max (validated r6-r11). S^T = K(A) x Q(B), pre-scaled via Wq fold.
// Layouts (m89/m120-verified): A[m=lane&15][k=quad*8+j];
// B[k=quad*8+j][n=lane&15]; C/D row=quad*4+reg, col=lane&15; K=16: k=quad*4+j.
// ---------------------------------------------------------------------------
__global__ __launch_bounds__(256, 4) void attn_flash(
    const bf16* __restrict__ qt, const bf16* __restrict__ kt,
    const bf16* __restrict__ v,  const bf16* __restrict__ wob,
    const float* __restrict__ x, float* __restrict__ out)
{
  __shared__ float obuf[64 * 132];          // 33792 B; ks/vs alias the front
  short* ks = (short*)obuf;                 // K tile [s][c]     (9216 B)
  short* vs = ks + 64 * 72;                 // V tile [c][s']    (9216 B)

  const int bid = blockIdx.x;
  const int n   = bid & 127;        // bid%8 == n%8 -> same-n blocks share an XCD
  const int qt0 = (bid >> 7) * 128;
  const int tid = threadIdx.x;
  const int w   = tid >> 6;
  const int il  = tid & 15;
  const int q4  = (tid & 63) >> 4;
  const size_t nbase = (size_t)n * (CC * TT);

  // staging coords: 2 chunks of 16B each for K and V
  const int srow0 = tid >> 3, scol = (tid & 7) * 8;
  const int srow1 = srow0 + 32;

  // persistent Q B-frags (pre-scaled): B[k=c][n=t], wave's 32 queries
  short8 qb[2][2];
  #pragma unroll
  for (int mt = 0; mt < 2; mt++)
    #pragma unroll
    for (int kk = 0; kk < 2; kk++)
      qb[mt][kk] = *(const short8*)&qt[nbase +
          (size_t)(qt0 + w * 32 + mt * 16 + il) * 64 + kk * 32 + q4 * 8];

  const short4v ones4 = { 0x3F80, 0x3F80, 0x3F80, 0x3F80 };  // bf16 1.0 x4

  f32x4 oaccT[2][4];                // [mt][ct]: O^T[c][t], c=ct*16+q4*4+r, t=mt*16+il
  f32x4 lacc[2];                    // denominator via ones-MFMA (all rows equal)
  #pragma unroll
  for (int mt = 0; mt < 2; mt++) {
    lacc[mt] = (f32x4){0.f, 0.f, 0.f, 0.f};
    #pragma unroll
    for (int ct = 0; ct < 4; ct++) oaccT[mt][ct] = (f32x4){0.f, 0.f, 0.f, 0.f};
  }

  // prefetch tile 0 into registers
  short8 kreg0 = *(const short8*)&kt[nbase + (size_t)srow0 * 64 + scol];
  short8 kreg1 = *(const short8*)&kt[nbase + (size_t)srow1 * 64 + scol];
  short8 vreg0 = *(const short8*)&v[nbase + (size_t)srow0 * TT + scol];
  short8 vreg1 = *(const short8*)&v[nbase + (size_t)srow1 * TT + scol];

  #pragma unroll 1
  for (int st = 0; st < 16; st++) {
    __syncthreads();                     // prev-iter compute reads of ks/vs done
    *(short8*)&ks[srow0 * 72 + scol] = kreg0;
    *(short8*)&ks[srow1 * 72 + scol] = kreg1;
    *(short8*)&vs[srow0 * 72 + scol] = vreg0;
    *(short8*)&vs[srow1 * 72 + scol] = vreg1;
    if (st < 15) {                       // prefetch st+1: in flight across barrier
      const int s1 = (st + 1) * 64;
      kreg0 = *(const short8*)&kt[nbase + (size_t)(s1 + srow0) * 64 + scol];
      kreg1 = *(const short8*)&kt[nbase + (size_t)(s1 + srow1) * 64 + scol];
      vreg0 = *(const short8*)&v[nbase + (size_t)srow0 * TT + s1 + scol];
      vreg1 = *(const short8*)&v[nbase + (size_t)srow1 * TT + s1 + scol];
    }
    __syncthreads();                     // ks/vs visible

    // ---- phase 1: S^T + exp -> P frags for all 4 strips (regs)
    short4v pf[2][4];
    #pragma unroll
    for (int st2 = 0; st2 < 4; st2++) {
      short8 ka0 = *(const short8*)&ks[(st2 * 16 + il) * 72 + q4 * 8];
      short8 ka1 = *(const short8*)&ks[(st2 * 16 + il) * 72 + 32 + q4 * 8];
      #pragma unroll
      for (int mt = 0; mt < 2; mt++) {
        f32x4 sT = (f32x4){0.f, 0.f, 0.f, 0.f};
        sT = mfma32(ka0, qb[mt][0], sT);
        sT = mfma32(ka1, qb[mt][1], sT);
        float p0 = EXP2(sT[0]), p1 = EXP2(sT[1]), p2 = EXP2(sT[2]), p3 = EXP2(sT[3]);
        unsigned pd[2] = { packbf2(rnd_u(p1), rnd_u(p0)),
                           packbf2(rnd_u(p3), rnd_u(p2)) };
        pf[mt][st2] = *(const short4v*)pd;
        lacc[mt] = mfma16(ones4, pf[mt][st2], lacc[mt]);   // row-sum on MFMA pipe
      }
    }

    // ---- phase 2: PV; permuted vs: one b128 = frags for strips {0,1} / {2,3}
    #pragma unroll
    for (int ct = 0; ct < 4; ct++) {
      short8 h0 = *(const short8*)&vs[(ct * 16 + il) * 72 + q4 * 16];
      short8 h1 = *(const short8*)&vs[(ct * 16 + il) * 72 + q4 * 16 + 8];
      short4v vf[4];
      #pragma unroll
      for (int j = 0; j < 4; j++) { vf[0][j] = h0[j]; vf[1][j] = h0[j + 4];
                                    vf[2][j] = h1[j]; vf[3][j] = h1[j + 4]; }
      #pragma unroll
      for (int st2 = 0; st2 < 4; st2++)
        #pragma unroll
        for (int mt = 0; mt < 2; mt++)
          oaccT[mt][ct] = mfma16(vf[st2], pf[mt][st2], oaccT[mt][ct]);
    }
  }

  // ================= epilogue ==============================================
  // l comes from lacc (all 4 rows equal = full sum over s for col t=il)
  float linv[2];
  #pragma unroll
  for (int mt = 0; mt < 2; mt++) linv[mt] = 1.f / lacc[mt][0];

  // O^T regs -> bf16 B-frags (k=c=q4*4+j == K=16 B layout)
  short4v ob[2][4];
  #pragma unroll
  for (int mt = 0; mt < 2; mt++)
    #pragma unroll
    for (int ct = 0; ct < 4; ct++)
      ob[mt][ct] = pack4(oaccT[mt][ct][0] * linv[mt], oaccT[mt][ct][1] * linv[mt],
                         oaccT[mt][ct][2] * linv[mt], oaccT[mt][ct][3] * linv[mt]);

  __syncthreads();   // all PV reads of ks/vs done before obuf overwrites them

  // res[o][t] = Wo(A) x O(B) -> obuf[o][t_local] (fp32, stride 132)
  #pragma unroll
  for (int ot = 0; ot < 4; ot++) {
    short4v wa[4];
    #pragma unroll
    for (int ct = 0; ct < 4; ct++)
      wa[ct] = *(const short4v*)&wob[(ot * 16 + il) * 64 + ct * 16 + q4 * 4];
    #pragma unroll
    for (int mt = 0; mt < 2; mt++) {
      f32x4 res = (f32x4){0.f, 0.f, 0.f, 0.f};
      #pragma unroll
      for (int ct = 0; ct < 4; ct++)
        res = mfma16(wa[ct], ob[mt][ct], res);
      #pragma unroll
      for (int r = 0; r < 4; r++)
        obuf[(ot * 16 + q4 * 4 + r) * 132 + w * 32 + mt * 16 + il] = res[r];
    }
  }
  __syncthreads();

  // coalesced store + residual: full 128B lines (8-lane groups x float4)
  const int orow = tid >> 3;          // 0..31
  const int ocb  = (tid & 7) * 4;     // col base
  #pragma unroll
  for (int half = 0; half < 2; half++) {
    const int row = orow + half * 32;
    #pragma unroll
    for (int k = 0; k < 4; k++) {
      const int col = ocb + k * 32;
      float4 val = *(const float4*)&obuf[row * 132 + col];
      const size_t idx = nbase + (size_t)row * TT + qt0 + col;
      float4 xv = *(const float4*)&x[idx];
      val.x += xv.x; val.y += xv.y; val.z += xv.z; val.w += xv.w;
      *(float4*)&out[idx] = val;
    }
  }
}

// ---------------------------------------------------------------------------
extern "C" void kernel_launch(void* const* d_in, const int* in_sizes, int n_in,
                              void* d_out, int out_size, void* d_ws, size_t ws_size,
                              hipStream_t stream) {
  const float* x     = (const float*)d_in[0];
  const float* Wq    = (const float*)d_in[1];
  const float* Wk    = (const float*)d_in[2];
  const float* Wv    = (const float*)d_in[3];
  const float* Wo    = (const float*)d_in[4];
  const float* scale = (const float*)d_in[5];
  float* out = (float*)d_out;

  const size_t elems = (size_t)NB * CC * TT;
  bf16* wb  = (bf16*)d_ws;          // 16384 bf16 weights
  bf16* qtb = wb + 16384;
  bf16* ktb = qtb + elems;
  bf16* vv  = ktb + elems;

  wcvt<<<64, 256, 0, stream>>>(Wq, Wk, Wv, Wo, scale, wb);
  qkv_mfma<<<dim3(TT / 64, NB), 256, 0, stream>>>(x, wb, qtb, ktb, vv);
  attn_flash<<<dim3(NB * (TT / 128)), 256, 0, stream>>>(qtb, ktb, vv, wb + 12288, x, out);
}